// Round 6
// baseline (227.889 us; speedup 1.0000x reference)
//
#include <hip/hip_runtime.h>
#include <hip/hip_bf16.h>

#define NN 2048
#define DD 512
#define NBATCH 4
#define KNB 10
#define NPAIR 45

typedef __attribute__((ext_vector_type(8))) short bf16x8;
typedef __attribute__((ext_vector_type(4))) float f32x4;

// ---------------------------------------------------------------------------
// helpers
// ---------------------------------------------------------------------------
__device__ __forceinline__ float tri_area(float p0x, float p0y, float p0z,
                                          float p1x, float p1y, float p1z,
                                          float p2x, float p2y, float p2z) {
    float e1x = __fsub_rn(p1x, p0x), e1y = __fsub_rn(p1y, p0y), e1z = __fsub_rn(p1z, p0z);
    float e2x = __fsub_rn(p2x, p0x), e2y = __fsub_rn(p2y, p0y), e2z = __fsub_rn(p2z, p0z);
    float c0 = __fsub_rn(__fmul_rn(e1y, e2z), __fmul_rn(e1z, e2y));
    float c1 = __fsub_rn(__fmul_rn(e1z, e2x), __fmul_rn(e1x, e2z));
    float c2 = __fsub_rn(__fmul_rn(e1x, e2y), __fmul_rn(e1y, e2x));
    float ss = __fadd_rn(__fadd_rn(__fmul_rn(c0, c0), __fmul_rn(c1, c1)), __fmul_rn(c2, c2));
    return __fmul_rn(0.5f, sqrtf(ss));
}

__device__ __forceinline__ double wave_red_sum_d(double v) {
#pragma unroll
    for (int st = 1; st < 64; st <<= 1) v += __shfl_xor(v, st, 64);
    return v;
}

// ---------------------------------------------------------------------------
// K0: prep_planes — convert f32 A/B to bf16 h/m planes, pre-tiled+pre-swizzled
// Layout: plane[((b*16 + kt)*2048 + row)*32 + ((g ^ ((row>>1)&3))<<3) + (k&7)]
// (exact LDS image for the GEMM's 8KB per-plane tiles)
// ---------------------------------------------------------------------------
__global__ __launch_bounds__(256) void prep_planes(const float* __restrict__ srcE,
                                                   const float* __restrict__ tgtE,
                                                   short* __restrict__ Ah, short* __restrict__ Am,
                                                   short* __restrict__ Bh, short* __restrict__ Bm) {
    int kt = blockIdx.x & 15, ng = blockIdx.x >> 4;
    int b = blockIdx.y, mat = blockIdx.z;
    int t = threadIdx.x;
    int gg = t & 3, nloc = t >> 2;
    int n = ng * 64 + nloc;
    int d0 = kt * 32 + gg * 8;
    const float* src = (mat ? tgtE : srcE) + (size_t)b * DD * NN;
    short* PH = mat ? Bh : Ah;
    short* PM = mat ? Bm : Am;

    float x[8];
#pragma unroll
    for (int j = 0; j < 8; j++) x[j] = src[(size_t)(d0 + j) * NN + n];
    unsigned h4[4], m4[4];
#pragma unroll
    for (int p = 0; p < 4; p++) {
        float x0 = x[2 * p], x1 = x[2 * p + 1];
        unsigned hp, mp;
        asm("v_cvt_pk_bf16_f32 %0, %1, %2" : "=v"(hp) : "v"(x0), "v"(x1));
        float h0 = __uint_as_float(hp << 16);
        float h1 = __uint_as_float(hp & 0xffff0000u);
        float r0 = __fsub_rn(x0, h0), r1 = __fsub_rn(x1, h1);
        asm("v_cvt_pk_bf16_f32 %0, %1, %2" : "=v"(mp) : "v"(r0), "v"(r1));
        h4[p] = hp; m4[p] = mp;
    }
    size_t o = ((size_t)(b * 16 + kt) * NN + n) * 32 + ((gg ^ ((n >> 1) & 3)) << 3);
    *(uint4*)&PH[o] = (uint4){h4[0], h4[1], h4[2], h4[3]};
    *(uint4*)&PM[o] = (uint4){m4[0], m4[1], m4[2], m4[3]};
}

// ---------------------------------------------------------------------------
// K1: fused MFMA GEMM (2-plane, 3-product) + online-softmax partial epilogue.
// 128x128 tile, BK=32, 4 waves. Staging via global_load_lds width=16 from the
// pre-swizzled planes (linear LDS dest; swizzle baked into global layout).
// Per wave 64-col span: per-row top-2/argmax + exp-sums -> 8-float partial.
// ---------------------------------------------------------------------------
__global__ __launch_bounds__(256) void gemm_fused(const short* __restrict__ Ah,
                                                  const short* __restrict__ Am,
                                                  const short* __restrict__ Bh,
                                                  const short* __restrict__ Bm,
                                                  const float* __restrict__ tgtP,
                                                  float* __restrict__ part) {
    int b = blockIdx.z;
    int n0 = blockIdx.y * 128, m0 = blockIdx.x * 128;
    __shared__ short LDS[4 * 4096];  // planes: 0=Ah 1=Am 2=Bh 3=Bm, 8KB each

    int t = threadIdx.x, w = t >> 6, lane = t & 63;
    int wr = w >> 1, wc = w & 1;
    int fr = lane & 15, kq = lane >> 4;

    const short* gpl[4] = {Ah, Am, Bh, Bm};

    f32x4 acc[4][4];
#pragma unroll
    for (int i = 0; i < 4; i++)
#pragma unroll
        for (int j = 0; j < 4; j++) acc[i][j] = (f32x4){0.f, 0.f, 0.f, 0.f};

    for (int kt = 0; kt < 16; kt++) {
        __syncthreads();  // protect previous iteration's fragment reads
#pragma unroll
        for (int q = 0; q < 8; q++) {
            int p = q >> 1, h = q & 1;
            int rb = (p < 2) ? n0 : m0;
            const short* g = gpl[p] + ((size_t)(b * 16 + kt) * NN + rb) * 32 +
                             h * 2048 + w * 512 + lane * 8;
            const short* l = &LDS[p * 4096 + h * 2048 + w * 512];
            __builtin_amdgcn_global_load_lds(
                (const __attribute__((address_space(1))) void*)g,
                (__attribute__((address_space(3))) void*)l, 16, 0, 0);
        }
        __syncthreads();  // compiler drains vmcnt(0) before barrier

        bf16x8 ah[4], am_[4], bh[4], bm_[4];
#pragma unroll
        for (int i = 0; i < 4; i++) {
            int rA = wr * 64 + i * 16 + fr;
            int offA = rA * 32 + ((kq ^ ((rA >> 1) & 3)) << 3);
            ah[i] = *(const bf16x8*)&LDS[offA];
            am_[i] = *(const bf16x8*)&LDS[4096 + offA];
            int rB = wc * 64 + i * 16 + fr;
            int offB = rB * 32 + ((kq ^ ((rB >> 1) & 3)) << 3);
            bh[i] = *(const bf16x8*)&LDS[2 * 4096 + offB];
            bm_[i] = *(const bf16x8*)&LDS[3 * 4096 + offB];
        }
#pragma unroll
        for (int i = 0; i < 4; i++)
#pragma unroll
            for (int j = 0; j < 4; j++) {
                f32x4 c = acc[i][j];
                c = __builtin_amdgcn_mfma_f32_16x16x32_bf16(ah[i], bh[j], c, 0, 0, 0);
                c = __builtin_amdgcn_mfma_f32_16x16x32_bf16(ah[i], bm_[j], c, 0, 0, 0);
                c = __builtin_amdgcn_mfma_f32_16x16x32_bf16(am_[i], bh[j], c, 0, 0, 0);
                acc[i][j] = c;
            }
    }

    // ---- online-softmax partial epilogue (per wave: 64 rows x 64 cols) ----
    const float* tb = tgtP + (size_t)b * 3 * NN;
    int colj[4];
    float tb0[4], tb1[4], tb2[4];
#pragma unroll
    for (int j = 0; j < 4; j++) {
        int col = m0 + wc * 64 + j * 16 + fr;
        colj[j] = col;
        tb0[j] = tb[col];
        tb1[j] = tb[NN + col];
        tb2[j] = tb[2 * NN + col];
    }
    int t32 = blockIdx.x * 2 + wc;
#pragma unroll
    for (int i = 0; i < 4; i++) {
#pragma unroll
        for (int rg = 0; rg < 4; rg++) {
            int row = n0 + wr * 64 + i * 16 + kq * 4 + rg;
            float sv[4];
#pragma unroll
            for (int j = 0; j < 4; j++)
                sv[j] = __fmul_rn(10000.0f, __fdiv_rn(acc[i][j][rg], 22.627416997969522f));
            // local top-2 (first-index on ties: j ascending = col ascending)
            float m1 = -3.4e38f, m2 = -3.4e38f;
            int i1 = 0x7fffffff;
#pragma unroll
            for (int j = 0; j < 4; j++) {
                float vv = sv[j];
                if (vv > m1) { m2 = m1; m1 = vv; i1 = colj[j]; }
                else if (vv > m2) m2 = vv;
            }
#pragma unroll
            for (int st = 1; st < 16; st <<= 1) {
                float om1 = __shfl_xor(m1, st, 64);
                float om2 = __shfl_xor(m2, st, 64);
                int oi1 = __shfl_xor(i1, st, 64);
                if (om1 > m1 || (om1 == m1 && oi1 < i1)) {
                    m2 = fmaxf(m1, om2); m1 = om1; i1 = oi1;
                } else {
                    m2 = fmaxf(om1, m2);
                }
            }
            float l = 0.f, c0 = 0.f, c1 = 0.f, c2 = 0.f;
#pragma unroll
            for (int j = 0; j < 4; j++) {
                float d = __fsub_rn(sv[j], m1);
                if (d >= -90.0f) {  // exp underflow vs max term — exact skip
                    float e = expf(d);
                    l = __fadd_rn(l, e);
                    c0 = fmaf(e, tb0[j], c0);
                    c1 = fmaf(e, tb1[j], c1);
                    c2 = fmaf(e, tb2[j], c2);
                }
            }
#pragma unroll
            for (int st = 1; st < 16; st <<= 1) {
                l += __shfl_xor(l, st, 64);
                c0 += __shfl_xor(c0, st, 64);
                c1 += __shfl_xor(c1, st, 64);
                c2 += __shfl_xor(c2, st, 64);
            }
            if (fr == 0) {
                size_t o = ((size_t)(b * NN + row) * 32 + t32) * 8;
                *(float4*)&part[o] = (float4){m1, m2, (float)i1, l};
                *(float4*)&part[o + 4] = (float4){c0, c1, c2, 0.f};
            }
        }
    }
}

// ---------------------------------------------------------------------------
// K2: combine 32 per-tile partials per row -> corres, flags, corrTgt
// ---------------------------------------------------------------------------
__global__ __launch_bounds__(256) void combine_rows(const float* __restrict__ part,
                                                    float* __restrict__ corrTgt,
                                                    int* __restrict__ corres,
                                                    int* __restrict__ flags) {
    int b = blockIdx.y;
    int w = threadIdx.x >> 6, lane = threadIdx.x & 63;
    int n = blockIdx.x * 4 + w;
    float m1 = -3.4e38f, m2 = -3.4e38f, l = 0.f, c0 = 0.f, c1 = 0.f, c2 = 0.f;
    int i1 = 0x7fffffff;
    if (lane < 32) {
        size_t o = ((size_t)(b * NN + n) * 32 + lane) * 8;
        float4 p1 = *(const float4*)&part[o];
        float4 p2 = *(const float4*)&part[o + 4];
        m1 = p1.x; m2 = p1.y; i1 = (int)p1.z; l = p1.w;
        c0 = p2.x; c1 = p2.y; c2 = p2.z;
    }
#pragma unroll
    for (int st = 1; st < 64; st <<= 1) {
        float om1 = __shfl_xor(m1, st, 64);
        float om2 = __shfl_xor(m2, st, 64);
        int oi1 = __shfl_xor(i1, st, 64);
        float ol = __shfl_xor(l, st, 64);
        float oc0 = __shfl_xor(c0, st, 64);
        float oc1 = __shfl_xor(c1, st, 64);
        float oc2 = __shfl_xor(c2, st, 64);
        if (om1 > m1 || (om1 == m1 && oi1 < i1)) {
            float sc = expf(m1 - om1);  // rescale own state
            m2 = fmaxf(m1, om2);
            l = ol + l * sc;
            c0 = oc0 + c0 * sc; c1 = oc1 + c1 * sc; c2 = oc2 + c2 * sc;
            m1 = om1; i1 = oi1;
        } else {
            float sc = expf(om1 - m1);
            m2 = fmaxf(om1, m2);
            l = l + ol * sc;
            c0 += oc0 * sc; c1 += oc1 * sc; c2 += oc2 * sc;
        }
    }
    if (lane == 0) {
        corres[b * NN + n] = i1;
        flags[b * NN + n] = (__fsub_rn(m1, m2) < 24.0f) ? 1 : 0;
        size_t o = ((size_t)b * NN + n) * 3;
        corrTgt[o + 0] = __fdiv_rn(c0, l);
        corrTgt[o + 1] = __fdiv_rn(c1, l);
        corrTgt[o + 2] = __fdiv_rn(c2, l);
    }
}

// ---------------------------------------------------------------------------
// K2b: exact f32 argmax recompute for flagged rows (atomicMax packed key)
// ---------------------------------------------------------------------------
__global__ __launch_bounds__(256) void refine_argmax(const float* __restrict__ A,
                                                     const float* __restrict__ Bm,
                                                     const int* __restrict__ flags,
                                                     unsigned long long* __restrict__ keys) {
    int row = blockIdx.y;
    if (!flags[row]) return;
    int b = row / NN, n = row % NN;
    int tid = threadIdx.x;
    __shared__ float Acol[DD];
    const float* Ab = A + (size_t)b * DD * NN;
    const float* Bb = Bm + (size_t)b * DD * NN;
    Acol[tid] = Ab[(size_t)tid * NN + n];
    Acol[tid + 256] = Ab[(size_t)(tid + 256) * NN + n];
    __syncthreads();
    int m = blockIdx.x * 256 + tid;
    float acc = 0.f;
    for (int d = 0; d < DD; d++) acc = fmaf(Acol[d], Bb[(size_t)d * NN + m], acc);
    float sc = __fmul_rn(10000.0f, __fdiv_rn(acc, 22.627416997969522f));
    unsigned u = __float_as_uint(sc);
    u = (u & 0x80000000u) ? ~u : (u | 0x80000000u);
    unsigned long long key = ((unsigned long long)u << 32) | (unsigned)(~(unsigned)m);
    atomicMax(&keys[row], key);
}

// ---------------------------------------------------------------------------
// K3: GFM wave-per-point (staged cloud in LDS, register top-10, rank sorts)
// ---------------------------------------------------------------------------
__global__ __launch_bounds__(256) void gfm_kernel(const float* __restrict__ srcP,
                                                  const float* __restrict__ corrTgt,
                                                  float* __restrict__ pointLoss) {
    int b = blockIdx.y, tid = threadIdx.x;
    int w = tid >> 6, lane = tid & 63;
    int n = blockIdx.x * 4 + w;
    __shared__ float X0[NN], X1[NN], X2[NN], SQ[NN];
    __shared__ int nbl[4][KNB];
    __shared__ float ptb[4][KNB][3];
    __shared__ float la[4][NPAIR], rg[4][NPAIR], srt[4][NPAIR];
    const float* xs = srcP + (size_t)b * 3 * NN;

    for (int i = tid; i < NN / 4; i += 256) {
        float4 u0 = ((const float4*)xs)[i];
        float4 u1 = ((const float4*)(xs + NN))[i];
        float4 u2 = ((const float4*)(xs + 2 * NN))[i];
        ((float4*)X0)[i] = u0;
        ((float4*)X1)[i] = u1;
        ((float4*)X2)[i] = u2;
        float4 q;
        q.x = __fadd_rn(__fadd_rn(__fmul_rn(u0.x, u0.x), __fmul_rn(u1.x, u1.x)), __fmul_rn(u2.x, u2.x));
        q.y = __fadd_rn(__fadd_rn(__fmul_rn(u0.y, u0.y), __fmul_rn(u1.y, u1.y)), __fmul_rn(u2.y, u2.y));
        q.z = __fadd_rn(__fadd_rn(__fmul_rn(u0.z, u0.z), __fmul_rn(u1.z, u1.z)), __fmul_rn(u2.z, u2.z));
        q.w = __fadd_rn(__fadd_rn(__fmul_rn(u0.w, u0.w), __fmul_rn(u1.w, u1.w)), __fmul_rn(u2.w, u2.w));
        ((float4*)SQ)[i] = q;
    }
    __syncthreads();

    float a0 = X0[n], a1 = X1[n], a2 = X2[n], sqa = SQ[n];
    float v[32];
#pragma unroll
    for (int r = 0; r < 32; r++) {
        int m = lane + 64 * r;
        float dot = __fadd_rn(__fadd_rn(__fmul_rn(a0, X0[m]), __fmul_rn(a1, X1[m])),
                              __fmul_rn(a2, X2[m]));
        float d2 = __fsub_rn(__fadd_rn(sqa, SQ[m]), __fmul_rn(2.0f, dot));
        v[r] = -fmaxf(d2, 0.0f);
    }
    unsigned removed = 0;
#pragma unroll
    for (int it = 0; it < KNB; it++) {
        float lm = -3.5e38f;
        int li = 0x7fffffff;
#pragma unroll
        for (int r = 0; r < 32; r++) {
            float vv = ((removed >> r) & 1u) ? -3.5e38f : v[r];
            int m = lane + 64 * r;
            if (vv > lm) { lm = vv; li = m; }
        }
#pragma unroll
        for (int st = 1; st < 64; st <<= 1) {
            float ov = __shfl_xor(lm, st, 64);
            int oi = __shfl_xor(li, st, 64);
            if (ov > lm || (ov == lm && oi < li)) { lm = ov; li = oi; }
        }
        if (lane == 0) nbl[w][it] = li;
        removed |= ((li & 63) == lane) ? (1u << (li >> 6)) : 0u;
    }
    __builtin_amdgcn_wave_barrier();
    if (lane < KNB) {
        int ia = nbl[w][lane];
        const float* ct = corrTgt + ((size_t)b * NN + ia) * 3;
        ptb[w][lane][0] = ct[0];
        ptb[w][lane][1] = ct[1];
        ptb[w][lane][2] = ct[2];
    }
    __builtin_amdgcn_wave_barrier();
    const float* ctn = corrTgt + ((size_t)b * NN + n) * 3;
    float t0 = ctn[0], t1 = ctn[1], t2 = ctn[2];
    if (lane < NPAIR) {
        int k = lane, ja = 0, cnt = 9;
        while (k >= cnt) { k -= cnt; ja++; cnt--; }
        int jb = ja + 1 + k;
        int ia = nbl[w][ja], ib = nbl[w][jb];
        float area_s = tri_area(a0, a1, a2, X0[ia], X1[ia], X2[ia], X0[ib], X1[ib], X2[ib]);
        float area_t = tri_area(t0, t1, t2, ptb[w][ja][0], ptb[w][ja][1], ptb[w][ja][2],
                                ptb[w][jb][0], ptb[w][jb][1], ptb[w][jb][2]);
        const float EPSF = 1e-6f;
        float ee = __fmul_rn(EPSF, EPSF);
        float lt2 = __fadd_rn(area_t, EPSF);
        float da = __fsub_rn(area_s, lt2);
        float sa = __fadd_rn(area_s, lt2);
        float num = __fadd_rn(__fadd_rn(ee, ee), __fmul_rn(da, da));
        float den = __fadd_rn(__fadd_rn(ee, ee), __fmul_rn(sa, sa));
        la[w][lane] = __fdiv_rn(num, den);
        rg[w][lane] = sqrtf(num);
    }
    __builtin_amdgcn_wave_barrier();
    if (lane < NPAIR) {
        float x = la[w][lane];
        int rk = 0;
        for (int j = 0; j < NPAIR; j++) {
            float y = la[w][j];
            rk += (y < x || (y == x && j < lane)) ? 1 : 0;
        }
        srt[w][rk] = x;
    }
    __builtin_amdgcn_wave_barrier();
    float l2v = 0.f;
    if (lane < NPAIR) l2v = __fadd_rn(srt[w][lane], __fmul_rn(0.1f, rg[w][lane]));
    __builtin_amdgcn_wave_barrier();
    if (lane < NPAIR) la[w][lane] = l2v;
    __builtin_amdgcn_wave_barrier();
    if (lane < NPAIR) {
        float x = la[w][lane];
        int rk = 0;
        for (int j = 0; j < NPAIR; j++) {
            float y = la[w][j];
            rk += (y < x || (y == x && j < lane)) ? 1 : 0;
        }
        srt[w][rk] = x;
    }
    __builtin_amdgcn_wave_barrier();
    float med = srt[w][22];
    float thr = __fmul_rn(3.0f, med);
    float term = 0.f;
    if (lane < KNB) {
        float vv = la[w][lane];
        if (vv > thr) vv = 0.f;
        term = sqrtf(__fadd_rn(vv, 1e-6f));
    }
#pragma unroll
    for (int st = 1; st < 64; st <<= 1) term += __shfl_xor(term, st, 64);
    if (lane == 0) pointLoss[b * NN + n] = __fdiv_rn(term, 10.0f);
}

// ---------------------------------------------------------------------------
// K4: per-batch min of pointLoss
// ---------------------------------------------------------------------------
__global__ __launch_bounds__(256) void min_kernel(const float* __restrict__ pl,
                                                  float* __restrict__ minL) {
    int b = blockIdx.x, tid = threadIdx.x;
    __shared__ float sd[256];
    float m = 3.4e38f;
    for (int n = tid; n < NN; n += 256) m = fminf(m, pl[b * NN + n]);
    sd[tid] = m;
    __syncthreads();
    for (int st = 128; st > 0; st >>= 1) {
        if (tid < st) sd[tid] = fminf(sd[tid], sd[tid + st]);
        __syncthreads();
    }
    if (tid == 0) minL[b] = sd[0];
}

// ---------------------------------------------------------------------------
// K5: weight + refined-corres unpack + f32 outputs
// ---------------------------------------------------------------------------
__global__ __launch_bounds__(256) void weight_kernel(const float* __restrict__ pl,
                                                     const float* __restrict__ minL,
                                                     int* __restrict__ corres,
                                                     const int* __restrict__ flags,
                                                     const unsigned long long* __restrict__ keys,
                                                     float* __restrict__ weight,
                                                     float* __restrict__ outC,
                                                     float* __restrict__ outW) {
    int i = blockIdx.x * 256 + threadIdx.x;
    if (i >= NBATCH * NN) return;
    int b = i / NN;
    int ci = corres[i];
    if (flags[i]) {
        ci = (int)(~(unsigned)(keys[i] & 0xFFFFFFFFull));
        corres[i] = ci;  // for proc_reduce
    }
    float l = __fsub_rn(pl[i], minL[b]);
    float z = __fmul_rn(-20.0f, l);
    float ez = expf(z);
    float sg = __fdiv_rn(ez, __fadd_rn(1.0f, ez));
    float w2 = __fmul_rn(2.0f, sg);
    float wf = (w2 > 0.5f) ? 1.0f : 0.0f;
    weight[i] = wf;
    outW[i] = wf;
    outC[i] = (float)ci;
}

// ---------------------------------------------------------------------------
// K6: per-batch Procrustes reductions (double, shuffle-based)
// ---------------------------------------------------------------------------
__global__ __launch_bounds__(256) void proc_reduce(const float* __restrict__ srcP,
                                                   const float* __restrict__ tgtP,
                                                   const int* __restrict__ corres,
                                                   const float* __restrict__ weight,
                                                   double* __restrict__ red) {
    int b = blockIdx.x, tid = threadIdx.x;
    int w = tid >> 6, lane = tid & 63;
    __shared__ double sd[4][9];
    const float* xs = srcP + (size_t)b * 3 * NN;
    const float* ts = tgtP + (size_t)b * 3 * NN;
    const int* cr = corres + b * NN;
    const float* wv = weight + b * NN;

    double acc7[7] = {0, 0, 0, 0, 0, 0, 0};
    for (int nn2 = tid; nn2 < NN; nn2 += 256) {
        if (wv[nn2] != 0.0f) {
            acc7[0] += 1.0;
            acc7[1] += (double)xs[nn2];
            acc7[2] += (double)xs[NN + nn2];
            acc7[3] += (double)xs[2 * NN + nn2];
            int m = cr[nn2];
            acc7[4] += (double)ts[m];
            acc7[5] += (double)ts[NN + m];
            acc7[6] += (double)ts[2 * NN + m];
        }
    }
#pragma unroll
    for (int q = 0; q < 7; q++) {
        double r = wave_red_sum_d(acc7[q]);
        if (lane == 0) sd[w][q] = r;
    }
    __syncthreads();
    double tot7[7];
#pragma unroll
    for (int q = 0; q < 7; q++) tot7[q] = sd[0][q] + sd[1][q] + sd[2][q] + sd[3][q];
    __syncthreads();

    double W1e = tot7[0] + 1e-7;
    double mux0 = tot7[1] / W1e, mux1 = tot7[2] / W1e, mux2 = tot7[3] / W1e;
    double muy0 = tot7[4] / W1e, muy1 = tot7[5] / W1e, muy2 = tot7[6] / W1e;

    double s[9] = {0, 0, 0, 0, 0, 0, 0, 0, 0};
    for (int nn2 = tid; nn2 < NN; nn2 += 256) {
        if (wv[nn2] != 0.0f) {
            double dx0 = (double)xs[nn2] - mux0;
            double dx1 = (double)xs[NN + nn2] - mux1;
            double dx2 = (double)xs[2 * NN + nn2] - mux2;
            int m = cr[nn2];
            double dy0 = (double)ts[m] - muy0;
            double dy1 = (double)ts[NN + m] - muy1;
            double dy2 = (double)ts[2 * NN + m] - muy2;
            s[0] += dy0 * dx0; s[1] += dy0 * dx1; s[2] += dy0 * dx2;
            s[3] += dy1 * dx0; s[4] += dy1 * dx1; s[5] += dy1 * dx2;
            s[6] += dy2 * dx0; s[7] += dy2 * dx1; s[8] += dy2 * dx2;
        }
    }
#pragma unroll
    for (int q = 0; q < 9; q++) {
        double r = wave_red_sum_d(s[q]);
        if (lane == 0) sd[w][q] = r;
    }
    __syncthreads();
    if (tid < 9) {
        double tot = sd[0][tid] + sd[1][tid] + sd[2][tid] + sd[3][tid];
        red[b * 16 + tid] = tot / W1e;
    }
    if (tid == 9) {
        red[b * 16 + 9] = mux0; red[b * 16 + 10] = mux1; red[b * 16 + 11] = mux2;
        red[b * 16 + 12] = muy0; red[b * 16 + 13] = muy1; red[b * 16 + 14] = muy2;
        red[b * 16 + 15] = W1e;
    }
}

// ---------------------------------------------------------------------------
// K7: 3x3 SVD (one-sided Jacobi, f64) -> R, T
// ---------------------------------------------------------------------------
__device__ double det3(const double M[3][3]) {
    return M[0][0] * (M[1][1] * M[2][2] - M[1][2] * M[2][1]) -
           M[0][1] * (M[1][0] * M[2][2] - M[1][2] * M[2][0]) +
           M[0][2] * (M[1][0] * M[2][1] - M[1][1] * M[2][0]);
}

__global__ void svd_finalize(const double* __restrict__ red,
                             float* __restrict__ outR,
                             float* __restrict__ outT) {
    int b = threadIdx.x;
    if (b >= NBATCH) return;
    double A[3][3], Bm[3][3], V[3][3];
    for (int r = 0; r < 3; r++)
        for (int c2 = 0; c2 < 3; c2++) {
            A[r][c2] = red[b * 16 + r * 3 + c2];
            Bm[r][c2] = A[r][c2];
            V[r][c2] = (r == c2) ? 1.0 : 0.0;
        }
    double nrm2 = 0;
    for (int r = 0; r < 3; r++)
        for (int c2 = 0; c2 < 3; c2++) nrm2 += Bm[r][c2] * Bm[r][c2];

    for (int sweep = 0; sweep < 60; sweep++) {
        double off = 0;
        for (int p = 0; p < 2; p++) {
            for (int q = p + 1; q < 3; q++) {
                double al = 0, be = 0, ga = 0;
                for (int i = 0; i < 3; i++) {
                    al += Bm[i][p] * Bm[i][p];
                    be += Bm[i][q] * Bm[i][q];
                    ga += Bm[i][p] * Bm[i][q];
                }
                off += ga * ga;
                if (fabs(ga) > 1e-300) {
                    double ze = (be - al) / (2.0 * ga);
                    double t = copysign(1.0, ze) / (fabs(ze) + sqrt(1.0 + ze * ze));
                    double c = 1.0 / sqrt(1.0 + t * t), sn = c * t;
                    for (int i = 0; i < 3; i++) {
                        double bp = Bm[i][p], bq = Bm[i][q];
                        Bm[i][p] = c * bp - sn * bq;
                        Bm[i][q] = sn * bp + c * bq;
                        double vp = V[i][p], vq = V[i][q];
                        V[i][p] = c * vp - sn * vq;
                        V[i][q] = sn * vp + c * vq;
                    }
                }
            }
        }
        if (off <= 1e-30 * nrm2 * nrm2) break;
    }
    double sig[3];
    for (int j = 0; j < 3; j++) {
        double ss = 0;
        for (int i = 0; i < 3; i++) ss += Bm[i][j] * Bm[i][j];
        sig[j] = sqrt(ss);
    }
    for (int a = 0; a < 2; a++)
        for (int j = 0; j < 2 - a; j++)
            if (sig[j] < sig[j + 1]) {
                double t = sig[j]; sig[j] = sig[j + 1]; sig[j + 1] = t;
                for (int i = 0; i < 3; i++) {
                    double tb = Bm[i][j]; Bm[i][j] = Bm[i][j + 1]; Bm[i][j + 1] = tb;
                    double tv = V[i][j]; V[i][j] = V[i][j + 1]; V[i][j + 1] = tv;
                }
            }
    double U[3][3];
    for (int j = 0; j < 3; j++) {
        double inv = (sig[j] > 1e-150) ? 1.0 / sig[j] : 0.0;
        for (int i = 0; i < 3; i++) U[i][j] = Bm[i][j] * inv;
    }
    if (sig[2] <= 1e-10 * (sig[0] + 1e-300)) {
        double u0 = U[1][0] * U[2][1] - U[2][0] * U[1][1];
        double u1 = U[2][0] * U[0][1] - U[0][0] * U[2][1];
        double u2 = U[0][0] * U[1][1] - U[1][0] * U[0][1];
        double nr = sqrt(u0 * u0 + u1 * u1 + u2 * u2);
        if (nr > 1e-150) { U[0][2] = u0 / nr; U[1][2] = u1 / nr; U[2][2] = u2 / nr; }
    }
    double dU = det3(U), dV = det3(V);
    double s3 = (dU * dV >= 0.0) ? 1.0 : -1.0;
    double R[3][3];
    for (int i = 0; i < 3; i++)
        for (int j = 0; j < 3; j++)
            R[i][j] = U[i][0] * V[j][0] + U[i][1] * V[j][1] + s3 * U[i][2] * V[j][2];
    double mux[3] = {red[b * 16 + 9], red[b * 16 + 10], red[b * 16 + 11]};
    double muy[3] = {red[b * 16 + 12], red[b * 16 + 13], red[b * 16 + 14]};
    for (int i = 0; i < 3; i++) {
        for (int j = 0; j < 3; j++) outR[b * 9 + i * 3 + j] = (float)R[i][j];
        double t = muy[i] - (R[i][0] * mux[0] + R[i][1] * mux[1] + R[i][2] * mux[2]);
        outT[b * 3 + i] = (float)t;
    }
}

// ---------------------------------------------------------------------------
// host launcher
// ---------------------------------------------------------------------------
extern "C" void kernel_launch(void* const* d_in, const int* in_sizes, int n_in,
                              void* d_out, int out_size, void* d_ws, size_t ws_size,
                              hipStream_t stream) {
    const float* srcE = (const float*)d_in[0];
    const float* tgtE = (const float*)d_in[1];
    const float* srcP = (const float*)d_in[2];
    const float* tgtP = (const float*)d_in[3];
    float* out = (float*)d_out;  // R[36] T[12] corres[8192] weight[8192]

    char* w = (char*)d_ws;
    size_t off = 0;
    auto alloc = [&](size_t bytes) -> void* {
        void* p = w + off;
        off = (off + bytes + 255) & ~(size_t)255;
        return p;
    };
    float* corrTgt = (float*)alloc((size_t)NBATCH * NN * 3 * 4);
    int* corres = (int*)alloc((size_t)NBATCH * NN * 4);
    int* flags = (int*)alloc((size_t)NBATCH * NN * 4);
    unsigned long long* keys = (unsigned long long*)alloc((size_t)NBATCH * NN * 8);
    float* pointLoss = (float*)alloc((size_t)NBATCH * NN * 4);
    float* minL = (float*)alloc(NBATCH * 4);
    float* weight = (float*)alloc((size_t)NBATCH * NN * 4);
    double* red = (double*)alloc(NBATCH * 16 * 8);
    size_t planeShorts = (size_t)NBATCH * 16 * NN * 32;  // 4.2M shorts = 8.4 MB
    short* Ah = (short*)alloc(planeShorts * 2);
    short* Am = (short*)alloc(planeShorts * 2);
    short* Bh = (short*)alloc(planeShorts * 2);
    short* Bm = (short*)alloc(planeShorts * 2);
    float* part = (float*)alloc((size_t)NBATCH * NN * 32 * 8 * 4);  // 8.4 MB

    hipMemsetAsync(keys, 0, (size_t)NBATCH * NN * 8, stream);

    prep_planes<<<dim3(512, NBATCH, 2), 256, 0, stream>>>(srcE, tgtE, Ah, Am, Bh, Bm);
    gemm_fused<<<dim3(NN / 128, NN / 128, NBATCH), 256, 0, stream>>>(Ah, Am, Bh, Bm, tgtP, part);
    combine_rows<<<dim3(NN / 4, NBATCH), 256, 0, stream>>>(part, corrTgt, corres, flags);
    refine_argmax<<<dim3(NN / 256, NBATCH * NN), 256, 0, stream>>>(srcE, tgtE, flags, keys);
    gfm_kernel<<<dim3(NN / 4, NBATCH), 256, 0, stream>>>(srcP, corrTgt, pointLoss);
    min_kernel<<<NBATCH, 256, 0, stream>>>(pointLoss, minL);
    weight_kernel<<<(NBATCH * NN + 255) / 256, 256, 0, stream>>>(
        pointLoss, minL, corres, flags, keys, weight, out + 48, out + 48 + NBATCH * NN);
    proc_reduce<<<NBATCH, 256, 0, stream>>>(srcP, tgtP, corres, weight, red);
    svd_finalize<<<1, 64, 0, stream>>>(red, out, out + 36);
}